// Round 14
// baseline (861.064 us; speedup 1.0000x reference)
//
#include <hip/hip_runtime.h>
#include <math.h>

// Problem constants: B=8, C=256, H=W=128
#define PIX 16384                       // H*W
#define TSZ ((size_t)33554432)          // 8*256*16384 elements per tensor

typedef __attribute__((ext_vector_type(8))) short  short8;   // 8 x bf16 (4 VGPRs)
typedef __attribute__((ext_vector_type(4))) float  float4v;
typedef __attribute__((ext_vector_type(4))) unsigned int uint4v;
typedef __attribute__((ext_vector_type(2))) unsigned int uint2v;

__device__ __forceinline__ unsigned short f2bf(float x) {
  unsigned int u = __float_as_uint(x);
  u += 0x7fffu + ((u >> 16) & 1u);      // round-to-nearest-even
  return (unsigned short)(u >> 16);
}
__device__ __forceinline__ float bf2f(unsigned short h) {
  return __uint_as_float(((unsigned int)h) << 16);
}
// pack two fp32 -> (bf16(hi)<<16)|bf16(lo) via v_perm_b32
__device__ __forceinline__ unsigned int pack_bf2(float lo, float hi) {
  unsigned int ul = __float_as_uint(lo); ul += 0x7fffu + ((ul >> 16) & 1u);
  unsigned int uh = __float_as_uint(hi); uh += 0x7fffu + ((uh >> 16) & 1u);
  return __builtin_amdgcn_perm(uh, ul, 0x07060302u);  // [ul.b2,ul.b3,uh.b2,uh.b3]
}

// order-preserving float<->uint for atomicMin/Max over signed floats
__device__ __forceinline__ unsigned int fkey(float f) {
  unsigned int u = __float_as_uint(f);
  return (u & 0x80000000u) ? ~u : (u | 0x80000000u);
}
__device__ __forceinline__ float funkey(unsigned int k) {
  unsigned int u = (k & 0x80000000u) ? (k ^ 0x80000000u) : ~k;
  return __uint_as_float(u);
}

#define SB0   __builtin_amdgcn_sched_barrier(0)
#define BARR  __builtin_amdgcn_s_barrier()
#define LGKM0 asm volatile("s_waitcnt lgkmcnt(0)" ::: "memory")
#define LGK(n) asm volatile("s_waitcnt lgkmcnt(" #n ")" ::: "memory")
#define VMC(n) asm volatile("s_waitcnt vmcnt(" #n ")" ::: "memory")

// ---------------------------------------------------------------------------
// Kernel 1: 7x7 patch stats + (merged) weight prep.
// R14 = R12 structure with __launch_bounds__(256,8): measured VGPR=48 and
// LDS=17.9KB allow 8 blocks/CU (8x17.9=143<=160KB; 48<=64-VGPR cap for 32
// waves/CU) -- R12's (256,4) capped residency at 16 waves (42% measured)
// for a latency-bound kernel. R6's spill trap doesn't apply: this structure
// compiles to 48 regs under a generous cap; 64-cap leaves headroom.
// Blocks >= 16384: weight pack + mmu key init.
// Output TILED: xcm[tens][b][pt(256)][k=c(256)][px(64)] bf16.
// ---------------------------------------------------------------------------
__global__ __launch_bounds__(256, 8) void k_stats(const float* __restrict__ front,
                                                  const float* __restrict__ back,
                                                  const float* __restrict__ we,
                                                  const float* __restrict__ wf,
                                                  const float* __restrict__ wg,
                                                  const float* __restrict__ wh,
                                                  unsigned short* __restrict__ xcm,
                                                  unsigned short* __restrict__ wbf,
                                                  unsigned int* __restrict__ mmu) {
  int blk = blockIdx.x;
  int t   = threadIdx.x;

  if (blk >= 16384) {                  // ---- weight-prep blocks ----
    if (blk == 16384 && t < 16)
      mmu[t] = (t & 1) ? 0u : 0xFFFFFFFFu;   // [2b]=min,[2b+1]=max keys
    int idx = (blk - 16384) * 256 + t;       // 0 .. 262143
    int g = idx >> 16, within = idx & 65535;
    const float* src = (g == 0) ? wf : (g == 1) ? wg : (g == 2) ? we : wh;
    int e    = within & 7;
    int lane = (within >> 3) & 63;
    int im   = (within >> 9) & 3;
    int wv   = (within >> 11) & 3;
    int i    = within >> 13;
    int col = lane & 15, q = lane >> 4;
    int m = wv * 64 + im * 16 + col;
    int k = i * 32 + q * 8 + e;
    wbf[idx] = f2bf(src[m * 256 + k]);
    return;
  }

  int s   = blk & 7;            // strip (16 rows)
  int c   = (blk >> 3) & 255;
  int b   = blk >> 11;
  int r0  = s * 16;

  __shared__ float2 vspD[16 * 137];        // 17.54 KB; cols 3..130 = -3..130 data, pads zeroed

  size_t planeOff = ((size_t)(b * 256 + c)) * PIX;

  float meanR[8], sdR[8];       // back stats, phase0 -> phase1 carry

  #pragma unroll 1
  for (int phase = 0; phase < 2; ++phase) {     // 0 = back, 1 = front
    const float* src = (phase == 0 ? back : front) + planeOff;
    // ---- vertical 7-tap sliding box sums: global -> registers -> vspD ----
    {
      int col = t & 127;
      int rg  = (t >> 7) * 8;                    // 8 output rows per thread
      const float* colp = src + col;
      float xv[14];                              // rows r0+rg-3 .. r0+rg+10
      #pragma unroll
      for (int j = 0; j < 14; ++j) {
        int g = r0 + rg - 3 + j;
        float v = 0.f;
        if (g >= 0 && g < 128) v = colp[g * 128];
        xv[j] = v;
      }
      float sm = 0.f, s2 = 0.f;
      #pragma unroll
      for (int j = 0; j < 7; ++j) { sm += xv[j]; s2 = fmaf(xv[j], xv[j], s2); }
      vspD[rg * 137 + col + 3] = make_float2(sm, s2);
      #pragma unroll
      for (int o = 1; o < 8; ++o) {
        float vn = xv[o + 6], vo = xv[o - 1];
        sm += vn - vo;
        s2 += vn * vn - vo * vo;
        vspD[(rg + o) * 137 + col + 3] = make_float2(sm, s2);
      }
      // zero pads: array cols 0,1,2 and 131,132,133 for all 16 rows
      if (t < 96) {
        int rr = t & 15;
        int pc = t >> 4;                         // 0..5
        int ac = (pc < 3) ? pc : 128 + pc;       // 0,1,2,131,132,133
        vspD[rr * 137 + ac] = make_float2(0.f, 0.f);
      }
    }
    LGKM0; BARR;
    // ---- horizontal 7-tap sliding window + finalize + DIRECT stores ----
    {
      int r  = t & 15;
      int c0 = (t >> 4) * 8;                     // 8 output cols per thread
      float2 w[14];
      #pragma unroll
      for (int i = 0; i < 14; ++i) w[i] = vspD[r * 137 + c0 + i];
      // center x values, re-read from global (L1-hot: just fetched above)
      float4v x0 = *(const float4v*)(src + (r0 + r) * 128 + c0);
      float4v x1 = *(const float4v*)(src + (r0 + r) * 128 + c0 + 4);
      float xc[8] = {x0[0], x0[1], x0[2], x0[3], x1[0], x1[1], x1[2], x1[3]};
      float sm = 0.f, s2 = 0.f;
      #pragma unroll
      for (int i = 0; i < 7; ++i) { sm += w[i].x; s2 += w[i].y; }
      float nrmv[8], hv[8];
      #pragma unroll
      for (int o = 0; o < 8; ++o) {
        float mean = sm * (1.f / 49.f);
        float var  = (s2 - sm * mean) * (1.f / 48.f);   // (s2 - s^2/49)/48
        var = var > 0.f ? var : 0.f;
        float sd = __builtin_amdgcn_sqrtf(var);
        float x  = xc[o];
        float nrm = (x - mean) * __builtin_amdgcn_rcpf(sd + 1e-8f);
        if (phase == 0) { meanR[o] = mean; sdR[o] = sd; hv[o] = x; }
        else            { hv[o] = nrm * sdR[o] + meanR[o]; }
        nrmv[o] = nrm;
        if (o < 7) { sm += w[o + 7].x - w[o].x; s2 += w[o + 7].y - w[o].y; }
      }
      uint4v nv  = (uint4v){pack_bf2(nrmv[0], nrmv[1]), pack_bf2(nrmv[2], nrmv[3]),
                            pack_bf2(nrmv[4], nrmv[5]), pack_bf2(nrmv[6], nrmv[7])};
      uint4v hvv = (uint4v){pack_bf2(hv[0], hv[1]), pack_bf2(hv[2], hv[3]),
                            pack_bf2(hv[4], hv[5]), pack_bf2(hv[6], hv[7])};
      // tiled store: p -> (pt=p>>6, pxi=p&63); addr = ((b*256+pt)*256+c)*64+pxi
      int p = (r0 + r) * 128 + c0;
      size_t gb2 = (((size_t)(b * 256 + (p >> 6))) * 256 + c) * 64 + (p & 63);
      int tn0 = (phase == 0) ? 1 : 0;
      int tn1 = (phase == 0) ? 3 : 2;
      *(uint4v*)(xcm + (size_t)tn0 * TSZ + gb2) = nv;
      *(uint4v*)(xcm + (size_t)tn1 * TSZ + gb2) = hvv;
    }
    LGKM0; BARR;   // all vspD reads done; next phase may overwrite
  }
}

// ---------------------------------------------------------------------------
// GEMM machinery (identical to R12: BK=64 superstep, counted-lgkm quads,
// (256,2), packed operands, tiled X).
// ---------------------------------------------------------------------------
__device__ __forceinline__ void stage_tile(const unsigned short* __restrict__ Xt,
                                           int k0, int t,
                                           unsigned short* dst) {
  int kk = ((t >> 5) << 2) + ((t & 7) >> 1);
  int px = (((t >> 3) & 3) << 4) + ((t & 1) << 3);
  const unsigned short* src = Xt + (size_t)(k0 << 6) + (kk << 6) + px;
  typedef const __attribute__((address_space(1))) unsigned int GUI;
  typedef __attribute__((address_space(3))) unsigned int LUI;
  __builtin_amdgcn_global_load_lds((GUI*)(unsigned long long)src,
                                   (LUI*)(unsigned)(unsigned long long)(dst + t * 8),
                                   16, 0, 0);
}

#define LOADA(S, I) {                                           \
  af[S][0] = *(const short8*)(Wr + (I) * 8192 + 0 * 512);       \
  af[S][1] = *(const short8*)(Wr + (I) * 8192 + 1 * 512);       \
  af[S][2] = *(const short8*)(Wr + (I) * 8192 + 2 * 512);       \
  af[S][3] = *(const short8*)(Wr + (I) * 8192 + 3 * 512); }

#define TR8(O0,O1,O2,O3,O4,O5,O6,O7)                                              \
  asm volatile("ds_read_b64_tr_b16 %0, %1 offset:" #O0 : "=v"(r0) : "v"(tra));    \
  asm volatile("ds_read_b64_tr_b16 %0, %1 offset:" #O1 : "=v"(r1) : "v"(tra));    \
  asm volatile("ds_read_b64_tr_b16 %0, %1 offset:" #O2 : "=v"(r2) : "v"(tra));    \
  asm volatile("ds_read_b64_tr_b16 %0, %1 offset:" #O3 : "=v"(r3) : "v"(tra));    \
  asm volatile("ds_read_b64_tr_b16 %0, %1 offset:" #O4 : "=v"(r4) : "v"(tra));    \
  asm volatile("ds_read_b64_tr_b16 %0, %1 offset:" #O5 : "=v"(r5) : "v"(tra));    \
  asm volatile("ds_read_b64_tr_b16 %0, %1 offset:" #O6 : "=v"(r6) : "v"(tra));    \
  asm volatile("ds_read_b64_tr_b16 %0, %1 offset:" #O7 : "=v"(r7) : "v"(tra));

#define QUAD(MS, IN, RA, RB) {                                              \
  union BU { unsigned u[4]; short8 s; } bu;                                 \
  bu.u[0] = RA[0]; bu.u[1] = RA[1]; bu.u[2] = RB[0]; bu.u[3] = RB[1];       \
  short8 bv = bu.s;                                                         \
  _Pragma("unroll")                                                         \
  for (int im = 0; im < 4; ++im)                                            \
    acc[IN][im] = __builtin_amdgcn_mfma_f32_16x16x32_bf16(af[MS][im], bv, acc[IN][im], 0, 0, 0); \
}

#define TRMFMA(MS, O0,O1,O2,O3,O4,O5,O6,O7)                                 \
  TR8(O0,O1,O2,O3,O4,O5,O6,O7);                                             \
  LGK(6); SB0; QUAD(MS, 0, r0, r1);                                         \
  LGK(4); SB0; QUAD(MS, 1, r2, r3);                                         \
  LGK(2); SB0; QUAD(MS, 2, r4, r5);                                         \
  LGK(0); SB0; QUAD(MS, 3, r6, r7);

__device__ __forceinline__ void gemm_pipe(const unsigned short* __restrict__ X,
                                          const unsigned short* __restrict__ Wm,
                                          unsigned short* xt, unsigned xbase,
                                          int mbase, int lane, int t,
                                          float4v acc[4][4]) {
  unsigned tra = xbase + (unsigned)((((lane >> 4)) << 10) + ((lane & 15) << 3));
  const unsigned short* __restrict__ Wr = Wm + ((mbase >> 6) << 11) + lane * 8;

  short8 af[2][4];
  uint2v r0, r1, r2, r3, r4, r5, r6, r7;

  #pragma unroll
  for (int in = 0; in < 4; ++in)
    #pragma unroll
    for (int im = 0; im < 4; ++im)
      acc[in][im] = (float4v){0.f, 0.f, 0.f, 0.f};

  SB0; BARR; SB0;
  stage_tile(X,   0, t, xt + 0 * 2048);
  stage_tile(X,  32, t, xt + 1 * 2048);
  stage_tile(X,  64, t, xt + 2 * 2048);
  stage_tile(X,  96, t, xt + 3 * 2048);
  SB0;

  // ---- SS0: tiles 0,1 ----
  LOADA(0, 0); LOADA(1, 1);
  SB0;
  stage_tile(X, 128, t, xt + 4 * 2048);
  stage_tile(X, 160, t, xt + 5 * 2048);
  SB0;
  VMC(2); SB0; BARR; SB0;
  TRMFMA(0,     0,   512,   128,   640,   256,   768,   384,   896)
  TRMFMA(1,  4096,  4608,  4224,  4736,  4352,  4864,  4480,  4992)

  // ---- SS1: tiles 2,3 ----
  SB0;
  LOADA(0, 2); LOADA(1, 3);
  SB0;
  stage_tile(X, 192, t, xt + 6 * 2048);
  stage_tile(X, 224, t, xt + 7 * 2048);
  SB0;
  VMC(2); SB0; BARR; SB0;
  TRMFMA(0,  8192,  8704,  8320,  8832,  8448,  8960,  8576,  9088)
  TRMFMA(1, 12288, 12800, 12416, 12928, 12544, 13056, 12672, 13184)

  // ---- SS2: tiles 4,5 ----
  SB0;
  LOADA(0, 4); LOADA(1, 5);
  SB0;
  VMC(0); SB0; BARR; SB0;
  TRMFMA(0, 16384, 16896, 16512, 17024, 16640, 17152, 16768, 17280)
  TRMFMA(1, 20480, 20992, 20608, 21120, 20736, 21248, 20864, 21376)

  // ---- SS3: tiles 6,7 ----
  SB0;
  LOADA(0, 6); LOADA(1, 7);
  SB0;
  VMC(0); SB0; BARR; SB0;
  TRMFMA(0, 24576, 25088, 24704, 25216, 24832, 25344, 24960, 25472)
  TRMFMA(1, 28672, 29184, 28800, 29312, 28928, 29440, 29056, 29568)
}

// ---------------------------------------------------------------------------
// Kernel 2a: FF/GG gemms -> cosine similarity S + atomic batch min/max.
// ---------------------------------------------------------------------------
__global__ __launch_bounds__(256, 2) void k_gemm1(const unsigned short* __restrict__ xcm,
                                                  const unsigned short* __restrict__ wbf,
                                                  const float* __restrict__ bFF,
                                                  const float* __restrict__ bGG,
                                                  float* __restrict__ Sout,
                                                  unsigned int* __restrict__ mmu) {
  int blk  = blockIdx.x;
  int b    = blk >> 8;
  int pt   = blk & 255;
  int p0   = pt * 64;
  int t    = threadIdx.x;
  int wv   = t >> 6;
  int lane = t & 63;
  int q    = lane >> 4;
  int mbase = wv * 64;

  __shared__ __align__(16) unsigned short xt[8][2048];   // 32 KB: 8 X slots
  __shared__ float sred[3 * 64];       // dot, |F|^2, |G|^2 per pixel
  if (t < 192) sred[t] = 0.f;
  __syncthreads();
  unsigned xbase = (unsigned)(unsigned long long)&xt[0][0];

  const unsigned short* Xt = xcm + (((size_t)(b * 256 + pt)) << 14);

  float4v aF[4][4], aG[4][4];

  gemm_pipe(Xt + 0 * TSZ, wbf + 0 * 65536, &xt[0][0], xbase, mbase, lane, t, aF);
  gemm_pipe(Xt + 1 * TSZ, wbf + 1 * 65536, &xt[0][0], xbase, mbase, lane, t, aG);
  #pragma unroll
  for (int im = 0; im < 4; ++im) {
    float4v bvF = *(const float4v*)(bFF + mbase + im * 16 + q * 4);
    float4v bvG = *(const float4v*)(bGG + mbase + im * 16 + q * 4);
    #pragma unroll
    for (int in = 0; in < 4; ++in) { aF[in][im] += bvF; aG[in][im] += bvG; }
  }
  #pragma unroll
  for (int in = 0; in < 4; ++in) {
    float d = 0.f, nf = 0.f, ng = 0.f;
    #pragma unroll
    for (int im = 0; im < 4; ++im)
      #pragma unroll
      for (int r = 0; r < 4; ++r) {
        float f = aF[in][im][r], g = aG[in][im][r];
        d += f * g; nf += f * f; ng += g * g;
      }
    d  += __shfl_xor(d, 16);  d  += __shfl_xor(d, 32);
    nf += __shfl_xor(nf, 16); nf += __shfl_xor(nf, 32);
    ng += __shfl_xor(ng, 16); ng += __shfl_xor(ng, 32);
    if (lane < 16) {
      atomicAdd(&sred[0 * 64 + in * 16 + lane], d);
      atomicAdd(&sred[1 * 64 + in * 16 + lane], nf);
      atomicAdd(&sred[2 * 64 + in * 16 + lane], ng);
    }
  }
  __syncthreads();
  if (t < 64) {           // wave 0
    float d = sred[t], nf = sred[64 + t], ng = sred[128 + t];
    float sv = d / (sqrtf(nf) * sqrtf(ng));
    Sout[(size_t)b * PIX + p0 + t] = sv;
    float mn = sv, mx = sv;
    #pragma unroll
    for (int o = 32; o >= 1; o >>= 1) {
      mn = fminf(mn, __shfl_xor(mn, o));
      mx = fmaxf(mx, __shfl_xor(mx, o));
    }
    if (t == 0) {
      atomicMin(&mmu[b * 2],     fkey(mn));
      atomicMax(&mmu[b * 2 + 1], fkey(mx));
    }
  }
}

// ---------------------------------------------------------------------------
// Kernel 2b: EE/HH gemms fused with the blend: out = S_n*EE + (1-S_n)*HH.
// ---------------------------------------------------------------------------
__global__ __launch_bounds__(256, 2) void k_gemm2(const unsigned short* __restrict__ xcm,
                                                  const unsigned short* __restrict__ wbf,
                                                  const float* __restrict__ bEE,
                                                  const float* __restrict__ bHH,
                                                  const float* __restrict__ S,
                                                  const unsigned int* __restrict__ mmu,
                                                  float* __restrict__ out) {
  int blk  = blockIdx.x;
  int b    = blk >> 8;
  int pt   = blk & 255;
  int p0   = pt * 64;
  int t    = threadIdx.x;
  int wv   = t >> 6;
  int lane = t & 63;
  int col  = lane & 15;
  int q    = lane >> 4;
  int mbase = wv * 64;

  __shared__ __align__(16) unsigned short xt[8][2048];   // 32 KB: 8 X slots
  unsigned xbase = (unsigned)(unsigned long long)&xt[0][0];

  const unsigned short* Xt = xcm + (((size_t)(b * 256 + pt)) << 14);

  float4v aE[4][4], aH[4][4];

  gemm_pipe(Xt + 2 * TSZ, wbf + 2 * 65536, &xt[0][0], xbase, mbase, lane, t, aE);
  gemm_pipe(Xt + 3 * TSZ, wbf + 3 * 65536, &xt[0][0], xbase, mbase, lane, t, aH);

  float mn = funkey(mmu[b * 2]), mx = funkey(mmu[b * 2 + 1]);
  float inv = 1.f / (mx - mn);
  float sn[4];
  #pragma unroll
  for (int in = 0; in < 4; ++in)
    sn[in] = (S[(size_t)b * PIX + p0 + in * 16 + col] - mn) * inv;

  #pragma unroll
  for (int im = 0; im < 4; ++im) {
    float4v bvE = *(const float4v*)(bEE + mbase + im * 16 + q * 4);
    float4v bvH = *(const float4v*)(bHH + mbase + im * 16 + q * 4);
    #pragma unroll
    for (int in = 0; in < 4; ++in)
      #pragma unroll
      for (int r = 0; r < 4; ++r) {
        int m = mbase + im * 16 + q * 4 + r;
        float e = aE[in][im][r] + bvE[r];
        float h = aH[in][im][r] + bvH[r];
        out[((size_t)(b * 256 + m)) * PIX + p0 + in * 16 + col] = h + sn[in] * (e - h);
      }
  }
}

// ---------------------------------------------------------------------------
// Workspace layout (bytes):
//   0          : xcm   4 tensors bf16 (tiled)    = 268,435,456
//   268435456  : wbf   4x256x256 bf16 (packed)   =     524,288
//   268959744  : S     fp32 8x16384              =     524,288
//   269484032  : mmu   u32 keys 8x2              =          64
// total ~269.5 MB
// ---------------------------------------------------------------------------
extern "C" void kernel_launch(void* const* d_in, const int* in_sizes, int n_in,
                              void* d_out, int out_size, void* d_ws, size_t ws_size,
                              hipStream_t stream) {
  const float* front = (const float*)d_in[0];
  const float* back  = (const float*)d_in[1];
  // d_in[2] = mask (unused by reference)
  const float* we = (const float*)d_in[3];
  const float* be = (const float*)d_in[4];
  const float* wf = (const float*)d_in[5];
  const float* bf = (const float*)d_in[6];
  const float* wg = (const float*)d_in[7];
  const float* bg = (const float*)d_in[8];
  const float* wh = (const float*)d_in[9];
  const float* bh = (const float*)d_in[10];

  char* ws = (char*)d_ws;
  unsigned short* xcm  = (unsigned short*)(ws);
  unsigned short* wbf  = (unsigned short*)(ws + 268435456);
  float*          S    = (float*)(ws + 268959744);
  unsigned int*   mmu  = (unsigned int*)(ws + 269484032);
  float*          out  = (float*)d_out;

  k_stats <<<17408, 256, 0, stream>>>(front, back, we, wf, wg, wh, xcm, wbf, mmu);
  k_gemm1 <<<2048,  256, 0, stream>>>(xcm, wbf, bf, bg, S, mmu);
  k_gemm2 <<<2048,  256, 0, stream>>>(xcm, wbf, be, bh, S, mmu, out);
}

// Round 15
// 616.153 us; speedup vs baseline: 1.3975x; 1.3975x over previous
//
#include <hip/hip_runtime.h>
#include <math.h>

// Problem constants: B=8, C=256, H=W=128
#define PIX 16384                       // H*W
#define TSZ ((size_t)33554432)          // 8*256*16384 elements per tensor

typedef __attribute__((ext_vector_type(8))) short  short8;   // 8 x bf16 (4 VGPRs)
typedef __attribute__((ext_vector_type(4))) float  float4v;
typedef __attribute__((ext_vector_type(4))) unsigned int uint4v;
typedef __attribute__((ext_vector_type(2))) unsigned int uint2v;

__device__ __forceinline__ unsigned short f2bf(float x) {
  unsigned int u = __float_as_uint(x);
  u += 0x7fffu + ((u >> 16) & 1u);      // round-to-nearest-even
  return (unsigned short)(u >> 16);
}
__device__ __forceinline__ float bf2f(unsigned short h) {
  return __uint_as_float(((unsigned int)h) << 16);
}
// pack two fp32 -> (bf16(hi)<<16)|bf16(lo) via v_perm_b32
__device__ __forceinline__ unsigned int pack_bf2(float lo, float hi) {
  unsigned int ul = __float_as_uint(lo); ul += 0x7fffu + ((ul >> 16) & 1u);
  unsigned int uh = __float_as_uint(hi); uh += 0x7fffu + ((uh >> 16) & 1u);
  return __builtin_amdgcn_perm(uh, ul, 0x07060302u);  // [ul.b2,ul.b3,uh.b2,uh.b3]
}

// order-preserving float<->uint for atomicMin/Max over signed floats
__device__ __forceinline__ unsigned int fkey(float f) {
  unsigned int u = __float_as_uint(f);
  return (u & 0x80000000u) ? ~u : (u | 0x80000000u);
}
__device__ __forceinline__ float funkey(unsigned int k) {
  unsigned int u = (k & 0x80000000u) ? (k ^ 0x80000000u) : ~k;
  return __uint_as_float(u);
}

#define SB0   __builtin_amdgcn_sched_barrier(0)
#define BARR  __builtin_amdgcn_s_barrier()
#define LGKM0 asm volatile("s_waitcnt lgkmcnt(0)" ::: "memory")
#define LGK(n) asm volatile("s_waitcnt lgkmcnt(" #n ")" ::: "memory")
#define VMC(n) asm volatile("s_waitcnt vmcnt(" #n ")" ::: "memory")

// ---------------------------------------------------------------------------
// Kernel 1: 7x7 patch stats + (merged) weight prep.
// R15 = R12 structure with __launch_bounds__(256,6): VGPR cap 512/6=85 --
// ~2x the 48-reg live set, so the allocator cannot be granule-rounded below
// need (R14's (256,8) cap of 64 rounded to 32 -> full spill). 6 blocks/CU =
// 24 waves (75%) vs R12's 16 (42% measured). LDS 6x17.9=107<=160KB.
// Blocks >= 16384: weight pack + mmu key init.
// Output TILED: xcm[tens][b][pt(256)][k=c(256)][px(64)] bf16.
// ---------------------------------------------------------------------------
__global__ __launch_bounds__(256, 6) void k_stats(const float* __restrict__ front,
                                                  const float* __restrict__ back,
                                                  const float* __restrict__ we,
                                                  const float* __restrict__ wf,
                                                  const float* __restrict__ wg,
                                                  const float* __restrict__ wh,
                                                  unsigned short* __restrict__ xcm,
                                                  unsigned short* __restrict__ wbf,
                                                  unsigned int* __restrict__ mmu) {
  int blk = blockIdx.x;
  int t   = threadIdx.x;

  if (blk >= 16384) {                  // ---- weight-prep blocks ----
    if (blk == 16384 && t < 16)
      mmu[t] = (t & 1) ? 0u : 0xFFFFFFFFu;   // [2b]=min,[2b+1]=max keys
    int idx = (blk - 16384) * 256 + t;       // 0 .. 262143
    int g = idx >> 16, within = idx & 65535;
    const float* src = (g == 0) ? wf : (g == 1) ? wg : (g == 2) ? we : wh;
    int e    = within & 7;
    int lane = (within >> 3) & 63;
    int im   = (within >> 9) & 3;
    int wv   = (within >> 11) & 3;
    int i    = within >> 13;
    int col = lane & 15, q = lane >> 4;
    int m = wv * 64 + im * 16 + col;
    int k = i * 32 + q * 8 + e;
    wbf[idx] = f2bf(src[m * 256 + k]);
    return;
  }

  int s   = blk & 7;            // strip (16 rows)
  int c   = (blk >> 3) & 255;
  int b   = blk >> 11;
  int r0  = s * 16;

  __shared__ float2 vspD[16 * 137];        // 17.54 KB; cols 3..130 = -3..130 data, pads zeroed

  size_t planeOff = ((size_t)(b * 256 + c)) * PIX;

  float meanR[8], sdR[8];       // back stats, phase0 -> phase1 carry

  #pragma unroll 1
  for (int phase = 0; phase < 2; ++phase) {     // 0 = back, 1 = front
    const float* src = (phase == 0 ? back : front) + planeOff;
    // ---- vertical 7-tap sliding box sums: global -> registers -> vspD ----
    {
      int col = t & 127;
      int rg  = (t >> 7) * 8;                    // 8 output rows per thread
      const float* colp = src + col;
      float xv[14];                              // rows r0+rg-3 .. r0+rg+10
      #pragma unroll
      for (int j = 0; j < 14; ++j) {
        int g = r0 + rg - 3 + j;
        float v = 0.f;
        if (g >= 0 && g < 128) v = colp[g * 128];
        xv[j] = v;
      }
      float sm = 0.f, s2 = 0.f;
      #pragma unroll
      for (int j = 0; j < 7; ++j) { sm += xv[j]; s2 = fmaf(xv[j], xv[j], s2); }
      vspD[rg * 137 + col + 3] = make_float2(sm, s2);
      #pragma unroll
      for (int o = 1; o < 8; ++o) {
        float vn = xv[o + 6], vo = xv[o - 1];
        sm += vn - vo;
        s2 += vn * vn - vo * vo;
        vspD[(rg + o) * 137 + col + 3] = make_float2(sm, s2);
      }
      // zero pads: array cols 0,1,2 and 131,132,133 for all 16 rows
      if (t < 96) {
        int rr = t & 15;
        int pc = t >> 4;                         // 0..5
        int ac = (pc < 3) ? pc : 128 + pc;       // 0,1,2,131,132,133
        vspD[rr * 137 + ac] = make_float2(0.f, 0.f);
      }
    }
    LGKM0; BARR;
    // ---- horizontal 7-tap sliding window + finalize + DIRECT stores ----
    {
      int r  = t & 15;
      int c0 = (t >> 4) * 8;                     // 8 output cols per thread
      float2 w[14];
      #pragma unroll
      for (int i = 0; i < 14; ++i) w[i] = vspD[r * 137 + c0 + i];
      // center x values, re-read from global (L1-hot: just fetched above)
      float4v x0 = *(const float4v*)(src + (r0 + r) * 128 + c0);
      float4v x1 = *(const float4v*)(src + (r0 + r) * 128 + c0 + 4);
      float xc[8] = {x0[0], x0[1], x0[2], x0[3], x1[0], x1[1], x1[2], x1[3]};
      float sm = 0.f, s2 = 0.f;
      #pragma unroll
      for (int i = 0; i < 7; ++i) { sm += w[i].x; s2 += w[i].y; }
      float nrmv[8], hv[8];
      #pragma unroll
      for (int o = 0; o < 8; ++o) {
        float mean = sm * (1.f / 49.f);
        float var  = (s2 - sm * mean) * (1.f / 48.f);   // (s2 - s^2/49)/48
        var = var > 0.f ? var : 0.f;
        float sd = __builtin_amdgcn_sqrtf(var);
        float x  = xc[o];
        float nrm = (x - mean) * __builtin_amdgcn_rcpf(sd + 1e-8f);
        if (phase == 0) { meanR[o] = mean; sdR[o] = sd; hv[o] = x; }
        else            { hv[o] = nrm * sdR[o] + meanR[o]; }
        nrmv[o] = nrm;
        if (o < 7) { sm += w[o + 7].x - w[o].x; s2 += w[o + 7].y - w[o].y; }
      }
      uint4v nv  = (uint4v){pack_bf2(nrmv[0], nrmv[1]), pack_bf2(nrmv[2], nrmv[3]),
                            pack_bf2(nrmv[4], nrmv[5]), pack_bf2(nrmv[6], nrmv[7])};
      uint4v hvv = (uint4v){pack_bf2(hv[0], hv[1]), pack_bf2(hv[2], hv[3]),
                            pack_bf2(hv[4], hv[5]), pack_bf2(hv[6], hv[7])};
      // tiled store: p -> (pt=p>>6, pxi=p&63); addr = ((b*256+pt)*256+c)*64+pxi
      int p = (r0 + r) * 128 + c0;
      size_t gb2 = (((size_t)(b * 256 + (p >> 6))) * 256 + c) * 64 + (p & 63);
      int tn0 = (phase == 0) ? 1 : 0;
      int tn1 = (phase == 0) ? 3 : 2;
      *(uint4v*)(xcm + (size_t)tn0 * TSZ + gb2) = nv;
      *(uint4v*)(xcm + (size_t)tn1 * TSZ + gb2) = hvv;
    }
    LGKM0; BARR;   // all vspD reads done; next phase may overwrite
  }
}

// ---------------------------------------------------------------------------
// GEMM machinery (identical to R12: BK=64 superstep, counted-lgkm quads,
// (256,2), packed operands, tiled X).
// ---------------------------------------------------------------------------
__device__ __forceinline__ void stage_tile(const unsigned short* __restrict__ Xt,
                                           int k0, int t,
                                           unsigned short* dst) {
  int kk = ((t >> 5) << 2) + ((t & 7) >> 1);
  int px = (((t >> 3) & 3) << 4) + ((t & 1) << 3);
  const unsigned short* src = Xt + (size_t)(k0 << 6) + (kk << 6) + px;
  typedef const __attribute__((address_space(1))) unsigned int GUI;
  typedef __attribute__((address_space(3))) unsigned int LUI;
  __builtin_amdgcn_global_load_lds((GUI*)(unsigned long long)src,
                                   (LUI*)(unsigned)(unsigned long long)(dst + t * 8),
                                   16, 0, 0);
}

#define LOADA(S, I) {                                           \
  af[S][0] = *(const short8*)(Wr + (I) * 8192 + 0 * 512);       \
  af[S][1] = *(const short8*)(Wr + (I) * 8192 + 1 * 512);       \
  af[S][2] = *(const short8*)(Wr + (I) * 8192 + 2 * 512);       \
  af[S][3] = *(const short8*)(Wr + (I) * 8192 + 3 * 512); }

#define TR8(O0,O1,O2,O3,O4,O5,O6,O7)                                              \
  asm volatile("ds_read_b64_tr_b16 %0, %1 offset:" #O0 : "=v"(r0) : "v"(tra));    \
  asm volatile("ds_read_b64_tr_b16 %0, %1 offset:" #O1 : "=v"(r1) : "v"(tra));    \
  asm volatile("ds_read_b64_tr_b16 %0, %1 offset:" #O2 : "=v"(r2) : "v"(tra));    \
  asm volatile("ds_read_b64_tr_b16 %0, %1 offset:" #O3 : "=v"(r3) : "v"(tra));    \
  asm volatile("ds_read_b64_tr_b16 %0, %1 offset:" #O4 : "=v"(r4) : "v"(tra));    \
  asm volatile("ds_read_b64_tr_b16 %0, %1 offset:" #O5 : "=v"(r5) : "v"(tra));    \
  asm volatile("ds_read_b64_tr_b16 %0, %1 offset:" #O6 : "=v"(r6) : "v"(tra));    \
  asm volatile("ds_read_b64_tr_b16 %0, %1 offset:" #O7 : "=v"(r7) : "v"(tra));

#define QUAD(MS, IN, RA, RB) {                                              \
  union BU { unsigned u[4]; short8 s; } bu;                                 \
  bu.u[0] = RA[0]; bu.u[1] = RA[1]; bu.u[2] = RB[0]; bu.u[3] = RB[1];       \
  short8 bv = bu.s;                                                         \
  _Pragma("unroll")                                                         \
  for (int im = 0; im < 4; ++im)                                            \
    acc[IN][im] = __builtin_amdgcn_mfma_f32_16x16x32_bf16(af[MS][im], bv, acc[IN][im], 0, 0, 0); \
}

#define TRMFMA(MS, O0,O1,O2,O3,O4,O5,O6,O7)                                 \
  TR8(O0,O1,O2,O3,O4,O5,O6,O7);                                             \
  LGK(6); SB0; QUAD(MS, 0, r0, r1);                                         \
  LGK(4); SB0; QUAD(MS, 1, r2, r3);                                         \
  LGK(2); SB0; QUAD(MS, 2, r4, r5);                                         \
  LGK(0); SB0; QUAD(MS, 3, r6, r7);

__device__ __forceinline__ void gemm_pipe(const unsigned short* __restrict__ X,
                                          const unsigned short* __restrict__ Wm,
                                          unsigned short* xt, unsigned xbase,
                                          int mbase, int lane, int t,
                                          float4v acc[4][4]) {
  unsigned tra = xbase + (unsigned)((((lane >> 4)) << 10) + ((lane & 15) << 3));
  const unsigned short* __restrict__ Wr = Wm + ((mbase >> 6) << 11) + lane * 8;

  short8 af[2][4];
  uint2v r0, r1, r2, r3, r4, r5, r6, r7;

  #pragma unroll
  for (int in = 0; in < 4; ++in)
    #pragma unroll
    for (int im = 0; im < 4; ++im)
      acc[in][im] = (float4v){0.f, 0.f, 0.f, 0.f};

  SB0; BARR; SB0;
  stage_tile(X,   0, t, xt + 0 * 2048);
  stage_tile(X,  32, t, xt + 1 * 2048);
  stage_tile(X,  64, t, xt + 2 * 2048);
  stage_tile(X,  96, t, xt + 3 * 2048);
  SB0;

  // ---- SS0: tiles 0,1 ----
  LOADA(0, 0); LOADA(1, 1);
  SB0;
  stage_tile(X, 128, t, xt + 4 * 2048);
  stage_tile(X, 160, t, xt + 5 * 2048);
  SB0;
  VMC(2); SB0; BARR; SB0;
  TRMFMA(0,     0,   512,   128,   640,   256,   768,   384,   896)
  TRMFMA(1,  4096,  4608,  4224,  4736,  4352,  4864,  4480,  4992)

  // ---- SS1: tiles 2,3 ----
  SB0;
  LOADA(0, 2); LOADA(1, 3);
  SB0;
  stage_tile(X, 192, t, xt + 6 * 2048);
  stage_tile(X, 224, t, xt + 7 * 2048);
  SB0;
  VMC(2); SB0; BARR; SB0;
  TRMFMA(0,  8192,  8704,  8320,  8832,  8448,  8960,  8576,  9088)
  TRMFMA(1, 12288, 12800, 12416, 12928, 12544, 13056, 12672, 13184)

  // ---- SS2: tiles 4,5 ----
  SB0;
  LOADA(0, 4); LOADA(1, 5);
  SB0;
  VMC(0); SB0; BARR; SB0;
  TRMFMA(0, 16384, 16896, 16512, 17024, 16640, 17152, 16768, 17280)
  TRMFMA(1, 20480, 20992, 20608, 21120, 20736, 21248, 20864, 21376)

  // ---- SS3: tiles 6,7 ----
  SB0;
  LOADA(0, 6); LOADA(1, 7);
  SB0;
  VMC(0); SB0; BARR; SB0;
  TRMFMA(0, 24576, 25088, 24704, 25216, 24832, 25344, 24960, 25472)
  TRMFMA(1, 28672, 29184, 28800, 29312, 28928, 29440, 29056, 29568)
}

// ---------------------------------------------------------------------------
// Kernel 2a: FF/GG gemms -> cosine similarity S + atomic batch min/max.
// ---------------------------------------------------------------------------
__global__ __launch_bounds__(256, 2) void k_gemm1(const unsigned short* __restrict__ xcm,
                                                  const unsigned short* __restrict__ wbf,
                                                  const float* __restrict__ bFF,
                                                  const float* __restrict__ bGG,
                                                  float* __restrict__ Sout,
                                                  unsigned int* __restrict__ mmu) {
  int blk  = blockIdx.x;
  int b    = blk >> 8;
  int pt   = blk & 255;
  int p0   = pt * 64;
  int t    = threadIdx.x;
  int wv   = t >> 6;
  int lane = t & 63;
  int q    = lane >> 4;
  int mbase = wv * 64;

  __shared__ __align__(16) unsigned short xt[8][2048];   // 32 KB: 8 X slots
  __shared__ float sred[3 * 64];       // dot, |F|^2, |G|^2 per pixel
  if (t < 192) sred[t] = 0.f;
  __syncthreads();
  unsigned xbase = (unsigned)(unsigned long long)&xt[0][0];

  const unsigned short* Xt = xcm + (((size_t)(b * 256 + pt)) << 14);

  float4v aF[4][4], aG[4][4];

  gemm_pipe(Xt + 0 * TSZ, wbf + 0 * 65536, &xt[0][0], xbase, mbase, lane, t, aF);
  gemm_pipe(Xt + 1 * TSZ, wbf + 1 * 65536, &xt[0][0], xbase, mbase, lane, t, aG);
  #pragma unroll
  for (int im = 0; im < 4; ++im) {
    float4v bvF = *(const float4v*)(bFF + mbase + im * 16 + q * 4);
    float4v bvG = *(const float4v*)(bGG + mbase + im * 16 + q * 4);
    #pragma unroll
    for (int in = 0; in < 4; ++in) { aF[in][im] += bvF; aG[in][im] += bvG; }
  }
  #pragma unroll
  for (int in = 0; in < 4; ++in) {
    float d = 0.f, nf = 0.f, ng = 0.f;
    #pragma unroll
    for (int im = 0; im < 4; ++im)
      #pragma unroll
      for (int r = 0; r < 4; ++r) {
        float f = aF[in][im][r], g = aG[in][im][r];
        d += f * g; nf += f * f; ng += g * g;
      }
    d  += __shfl_xor(d, 16);  d  += __shfl_xor(d, 32);
    nf += __shfl_xor(nf, 16); nf += __shfl_xor(nf, 32);
    ng += __shfl_xor(ng, 16); ng += __shfl_xor(ng, 32);
    if (lane < 16) {
      atomicAdd(&sred[0 * 64 + in * 16 + lane], d);
      atomicAdd(&sred[1 * 64 + in * 16 + lane], nf);
      atomicAdd(&sred[2 * 64 + in * 16 + lane], ng);
    }
  }
  __syncthreads();
  if (t < 64) {           // wave 0
    float d = sred[t], nf = sred[64 + t], ng = sred[128 + t];
    float sv = d / (sqrtf(nf) * sqrtf(ng));
    Sout[(size_t)b * PIX + p0 + t] = sv;
    float mn = sv, mx = sv;
    #pragma unroll
    for (int o = 32; o >= 1; o >>= 1) {
      mn = fminf(mn, __shfl_xor(mn, o));
      mx = fmaxf(mx, __shfl_xor(mx, o));
    }
    if (t == 0) {
      atomicMin(&mmu[b * 2],     fkey(mn));
      atomicMax(&mmu[b * 2 + 1], fkey(mx));
    }
  }
}

// ---------------------------------------------------------------------------
// Kernel 2b: EE/HH gemms fused with the blend: out = S_n*EE + (1-S_n)*HH.
// ---------------------------------------------------------------------------
__global__ __launch_bounds__(256, 2) void k_gemm2(const unsigned short* __restrict__ xcm,
                                                  const unsigned short* __restrict__ wbf,
                                                  const float* __restrict__ bEE,
                                                  const float* __restrict__ bHH,
                                                  const float* __restrict__ S,
                                                  const unsigned int* __restrict__ mmu,
                                                  float* __restrict__ out) {
  int blk  = blockIdx.x;
  int b    = blk >> 8;
  int pt   = blk & 255;
  int p0   = pt * 64;
  int t    = threadIdx.x;
  int wv   = t >> 6;
  int lane = t & 63;
  int col  = lane & 15;
  int q    = lane >> 4;
  int mbase = wv * 64;

  __shared__ __align__(16) unsigned short xt[8][2048];   // 32 KB: 8 X slots
  unsigned xbase = (unsigned)(unsigned long long)&xt[0][0];

  const unsigned short* Xt = xcm + (((size_t)(b * 256 + pt)) << 14);

  float4v aE[4][4], aH[4][4];

  gemm_pipe(Xt + 2 * TSZ, wbf + 2 * 65536, &xt[0][0], xbase, mbase, lane, t, aE);
  gemm_pipe(Xt + 3 * TSZ, wbf + 3 * 65536, &xt[0][0], xbase, mbase, lane, t, aH);

  float mn = funkey(mmu[b * 2]), mx = funkey(mmu[b * 2 + 1]);
  float inv = 1.f / (mx - mn);
  float sn[4];
  #pragma unroll
  for (int in = 0; in < 4; ++in)
    sn[in] = (S[(size_t)b * PIX + p0 + in * 16 + col] - mn) * inv;

  #pragma unroll
  for (int im = 0; im < 4; ++im) {
    float4v bvE = *(const float4v*)(bEE + mbase + im * 16 + q * 4);
    float4v bvH = *(const float4v*)(bHH + mbase + im * 16 + q * 4);
    #pragma unroll
    for (int in = 0; in < 4; ++in)
      #pragma unroll
      for (int r = 0; r < 4; ++r) {
        int m = mbase + im * 16 + q * 4 + r;
        float e = aE[in][im][r] + bvE[r];
        float h = aH[in][im][r] + bvH[r];
        out[((size_t)(b * 256 + m)) * PIX + p0 + in * 16 + col] = h + sn[in] * (e - h);
      }
  }
}

// ---------------------------------------------------------------------------
// Workspace layout (bytes):
//   0          : xcm   4 tensors bf16 (tiled)    = 268,435,456
//   268435456  : wbf   4x256x256 bf16 (packed)   =     524,288
//   268959744  : S     fp32 8x16384              =     524,288
//   269484032  : mmu   u32 keys 8x2              =          64
// total ~269.5 MB
// ---------------------------------------------------------------------------
extern "C" void kernel_launch(void* const* d_in, const int* in_sizes, int n_in,
                              void* d_out, int out_size, void* d_ws, size_t ws_size,
                              hipStream_t stream) {
  const float* front = (const float*)d_in[0];
  const float* back  = (const float*)d_in[1];
  // d_in[2] = mask (unused by reference)
  const float* we = (const float*)d_in[3];
  const float* be = (const float*)d_in[4];
  const float* wf = (const float*)d_in[5];
  const float* bf = (const float*)d_in[6];
  const float* wg = (const float*)d_in[7];
  const float* bg = (const float*)d_in[8];
  const float* wh = (const float*)d_in[9];
  const float* bh = (const float*)d_in[10];

  char* ws = (char*)d_ws;
  unsigned short* xcm  = (unsigned short*)(ws);
  unsigned short* wbf  = (unsigned short*)(ws + 268435456);
  float*          S    = (float*)(ws + 268959744);
  unsigned int*   mmu  = (unsigned int*)(ws + 269484032);
  float*          out  = (float*)d_out;

  k_stats <<<17408, 256, 0, stream>>>(front, back, we, wf, wg, wh, xcm, wbf, mmu);
  k_gemm1 <<<2048,  256, 0, stream>>>(xcm, wbf, bf, bg, S, mmu);
  k_gemm2 <<<2048,  256, 0, stream>>>(xcm, wbf, be, bh, S, mmu, out);
}

// Round 16
// 503.223 us; speedup vs baseline: 1.7111x; 1.2244x over previous
//
#include <hip/hip_runtime.h>
#include <math.h>

// Problem constants: B=8, C=256, H=W=128
#define PIX 16384                       // H*W
#define TSZ ((size_t)33554432)          // 8*256*16384 elements per tensor

typedef __attribute__((ext_vector_type(8))) short  short8;   // 8 x bf16 (4 VGPRs)
typedef __attribute__((ext_vector_type(4))) float  float4v;
typedef __attribute__((ext_vector_type(4))) unsigned int uint4v;
typedef __attribute__((ext_vector_type(2))) unsigned int uint2v;

__device__ __forceinline__ unsigned short f2bf(float x) {
  unsigned int u = __float_as_uint(x);
  u += 0x7fffu + ((u >> 16) & 1u);      // round-to-nearest-even
  return (unsigned short)(u >> 16);
}
__device__ __forceinline__ float bf2f(unsigned short h) {
  return __uint_as_float(((unsigned int)h) << 16);
}
// pack two fp32 -> (bf16(hi)<<16)|bf16(lo) via v_perm_b32
__device__ __forceinline__ unsigned int pack_bf2(float lo, float hi) {
  unsigned int ul = __float_as_uint(lo); ul += 0x7fffu + ((ul >> 16) & 1u);
  unsigned int uh = __float_as_uint(hi); uh += 0x7fffu + ((uh >> 16) & 1u);
  return __builtin_amdgcn_perm(uh, ul, 0x07060302u);  // [ul.b2,ul.b3,uh.b2,uh.b3]
}

// order-preserving float<->uint for atomicMin/Max over signed floats
__device__ __forceinline__ unsigned int fkey(float f) {
  unsigned int u = __float_as_uint(f);
  return (u & 0x80000000u) ? ~u : (u | 0x80000000u);
}
__device__ __forceinline__ float funkey(unsigned int k) {
  unsigned int u = (k & 0x80000000u) ? (k ^ 0x80000000u) : ~k;
  return __uint_as_float(u);
}

#define SB0   __builtin_amdgcn_sched_barrier(0)
#define BARR  __builtin_amdgcn_s_barrier()
#define LGKM0 asm volatile("s_waitcnt lgkmcnt(0)" ::: "memory")
#define LGK(n) asm volatile("s_waitcnt lgkmcnt(" #n ")" ::: "memory")
#define VMC(n) asm volatile("s_waitcnt vmcnt(" #n ")" ::: "memory")

// ---------------------------------------------------------------------------
// Kernel 1: 7x7 patch stats + (merged) weight prep.  [R12 config, VERIFIED
// best: 504.7us total, k_stats 149us, VGPR 48, no spill at (256,4).]
// Blocks >= 16384: pack the four 256x256 weight matrices to bf16
// (wpk[g][i=kstep(8)][wv(4)][im(4)][lane(64)][e(8)]) and init mmu keys.
// Blocks < 16384: stats (no xs LDS; global-direct reads; direct stores).
// Occupancy ladder closed: (256,6/7/8) all spill (allocator granule rounds
// below the ~48-reg live set); (256,4) is the optimum.
// Output TILED: xcm[tens][b][pt(256)][k=c(256)][px(64)] bf16.
// ---------------------------------------------------------------------------
__global__ __launch_bounds__(256, 4) void k_stats(const float* __restrict__ front,
                                                  const float* __restrict__ back,
                                                  const float* __restrict__ we,
                                                  const float* __restrict__ wf,
                                                  const float* __restrict__ wg,
                                                  const float* __restrict__ wh,
                                                  unsigned short* __restrict__ xcm,
                                                  unsigned short* __restrict__ wbf,
                                                  unsigned int* __restrict__ mmu) {
  int blk = blockIdx.x;
  int t   = threadIdx.x;

  if (blk >= 16384) {                  // ---- weight-prep blocks ----
    if (blk == 16384 && t < 16)
      mmu[t] = (t & 1) ? 0u : 0xFFFFFFFFu;   // [2b]=min,[2b+1]=max keys
    int idx = (blk - 16384) * 256 + t;       // 0 .. 262143
    int g = idx >> 16, within = idx & 65535;
    const float* src = (g == 0) ? wf : (g == 1) ? wg : (g == 2) ? we : wh;
    int e    = within & 7;
    int lane = (within >> 3) & 63;
    int im   = (within >> 9) & 3;
    int wv   = (within >> 11) & 3;
    int i    = within >> 13;
    int col = lane & 15, q = lane >> 4;
    int m = wv * 64 + im * 16 + col;
    int k = i * 32 + q * 8 + e;
    wbf[idx] = f2bf(src[m * 256 + k]);
    return;
  }

  int s   = blk & 7;            // strip (16 rows)
  int c   = (blk >> 3) & 255;
  int b   = blk >> 11;
  int r0  = s * 16;

  __shared__ float2 vspD[16 * 137];        // 17.54 KB; cols 3..130 = -3..130 data, pads zeroed

  size_t planeOff = ((size_t)(b * 256 + c)) * PIX;

  float meanR[8], sdR[8];       // back stats, phase0 -> phase1 carry

  #pragma unroll 1
  for (int phase = 0; phase < 2; ++phase) {     // 0 = back, 1 = front
    const float* src = (phase == 0 ? back : front) + planeOff;
    // ---- vertical 7-tap sliding box sums: global -> registers -> vspD ----
    {
      int col = t & 127;
      int rg  = (t >> 7) * 8;                    // 8 output rows per thread
      const float* colp = src + col;
      float xv[14];                              // rows r0+rg-3 .. r0+rg+10
      #pragma unroll
      for (int j = 0; j < 14; ++j) {
        int g = r0 + rg - 3 + j;
        float v = 0.f;
        if (g >= 0 && g < 128) v = colp[g * 128];
        xv[j] = v;
      }
      float sm = 0.f, s2 = 0.f;
      #pragma unroll
      for (int j = 0; j < 7; ++j) { sm += xv[j]; s2 = fmaf(xv[j], xv[j], s2); }
      vspD[rg * 137 + col + 3] = make_float2(sm, s2);
      #pragma unroll
      for (int o = 1; o < 8; ++o) {
        float vn = xv[o + 6], vo = xv[o - 1];
        sm += vn - vo;
        s2 += vn * vn - vo * vo;
        vspD[(rg + o) * 137 + col + 3] = make_float2(sm, s2);
      }
      // zero pads: array cols 0,1,2 and 131,132,133 for all 16 rows
      if (t < 96) {
        int rr = t & 15;
        int pc = t >> 4;                         // 0..5
        int ac = (pc < 3) ? pc : 128 + pc;       // 0,1,2,131,132,133
        vspD[rr * 137 + ac] = make_float2(0.f, 0.f);
      }
    }
    LGKM0; BARR;
    // ---- horizontal 7-tap sliding window + finalize + DIRECT stores ----
    {
      int r  = t & 15;
      int c0 = (t >> 4) * 8;                     // 8 output cols per thread
      float2 w[14];
      #pragma unroll
      for (int i = 0; i < 14; ++i) w[i] = vspD[r * 137 + c0 + i];
      // center x values, re-read from global (L1-hot: just fetched above)
      float4v x0 = *(const float4v*)(src + (r0 + r) * 128 + c0);
      float4v x1 = *(const float4v*)(src + (r0 + r) * 128 + c0 + 4);
      float xc[8] = {x0[0], x0[1], x0[2], x0[3], x1[0], x1[1], x1[2], x1[3]};
      float sm = 0.f, s2 = 0.f;
      #pragma unroll
      for (int i = 0; i < 7; ++i) { sm += w[i].x; s2 += w[i].y; }
      float nrmv[8], hv[8];
      #pragma unroll
      for (int o = 0; o < 8; ++o) {
        float mean = sm * (1.f / 49.f);
        float var  = (s2 - sm * mean) * (1.f / 48.f);   // (s2 - s^2/49)/48
        var = var > 0.f ? var : 0.f;
        float sd = __builtin_amdgcn_sqrtf(var);
        float x  = xc[o];
        float nrm = (x - mean) * __builtin_amdgcn_rcpf(sd + 1e-8f);
        if (phase == 0) { meanR[o] = mean; sdR[o] = sd; hv[o] = x; }
        else            { hv[o] = nrm * sdR[o] + meanR[o]; }
        nrmv[o] = nrm;
        if (o < 7) { sm += w[o + 7].x - w[o].x; s2 += w[o + 7].y - w[o].y; }
      }
      uint4v nv  = (uint4v){pack_bf2(nrmv[0], nrmv[1]), pack_bf2(nrmv[2], nrmv[3]),
                            pack_bf2(nrmv[4], nrmv[5]), pack_bf2(nrmv[6], nrmv[7])};
      uint4v hvv = (uint4v){pack_bf2(hv[0], hv[1]), pack_bf2(hv[2], hv[3]),
                            pack_bf2(hv[4], hv[5]), pack_bf2(hv[6], hv[7])};
      // tiled store: p -> (pt=p>>6, pxi=p&63); addr = ((b*256+pt)*256+c)*64+pxi
      int p = (r0 + r) * 128 + c0;
      size_t gb2 = (((size_t)(b * 256 + (p >> 6))) * 256 + c) * 64 + (p & 63);
      int tn0 = (phase == 0) ? 1 : 0;
      int tn1 = (phase == 0) ? 3 : 2;
      *(uint4v*)(xcm + (size_t)tn0 * TSZ + gb2) = nv;
      *(uint4v*)(xcm + (size_t)tn1 * TSZ + gb2) = hvv;
    }
    LGKM0; BARR;   // all vspD reads done; next phase may overwrite
  }
}

// ---------------------------------------------------------------------------
// GEMM machinery (R12: BK=64 superstep, counted-lgkm quads, (256,2),
// packed operands, tiled X). Register wall: acc 128 AGPR + ~116 arch = 244
// of 256 at 2 blocks/CU -- 3+ blocks/CU spills (R8/R9/R15-class evidence).
// ---------------------------------------------------------------------------
__device__ __forceinline__ void stage_tile(const unsigned short* __restrict__ Xt,
                                           int k0, int t,
                                           unsigned short* dst) {
  int kk = ((t >> 5) << 2) + ((t & 7) >> 1);
  int px = (((t >> 3) & 3) << 4) + ((t & 1) << 3);
  const unsigned short* src = Xt + (size_t)(k0 << 6) + (kk << 6) + px;
  typedef const __attribute__((address_space(1))) unsigned int GUI;
  typedef __attribute__((address_space(3))) unsigned int LUI;
  __builtin_amdgcn_global_load_lds((GUI*)(unsigned long long)src,
                                   (LUI*)(unsigned)(unsigned long long)(dst + t * 8),
                                   16, 0, 0);
}

#define LOADA(S, I) {                                           \
  af[S][0] = *(const short8*)(Wr + (I) * 8192 + 0 * 512);       \
  af[S][1] = *(const short8*)(Wr + (I) * 8192 + 1 * 512);       \
  af[S][2] = *(const short8*)(Wr + (I) * 8192 + 2 * 512);       \
  af[S][3] = *(const short8*)(Wr + (I) * 8192 + 3 * 512); }

#define TR8(O0,O1,O2,O3,O4,O5,O6,O7)                                              \
  asm volatile("ds_read_b64_tr_b16 %0, %1 offset:" #O0 : "=v"(r0) : "v"(tra));    \
  asm volatile("ds_read_b64_tr_b16 %0, %1 offset:" #O1 : "=v"(r1) : "v"(tra));    \
  asm volatile("ds_read_b64_tr_b16 %0, %1 offset:" #O2 : "=v"(r2) : "v"(tra));    \
  asm volatile("ds_read_b64_tr_b16 %0, %1 offset:" #O3 : "=v"(r3) : "v"(tra));    \
  asm volatile("ds_read_b64_tr_b16 %0, %1 offset:" #O4 : "=v"(r4) : "v"(tra));    \
  asm volatile("ds_read_b64_tr_b16 %0, %1 offset:" #O5 : "=v"(r5) : "v"(tra));    \
  asm volatile("ds_read_b64_tr_b16 %0, %1 offset:" #O6 : "=v"(r6) : "v"(tra));    \
  asm volatile("ds_read_b64_tr_b16 %0, %1 offset:" #O7 : "=v"(r7) : "v"(tra));

#define QUAD(MS, IN, RA, RB) {                                              \
  union BU { unsigned u[4]; short8 s; } bu;                                 \
  bu.u[0] = RA[0]; bu.u[1] = RA[1]; bu.u[2] = RB[0]; bu.u[3] = RB[1];       \
  short8 bv = bu.s;                                                         \
  _Pragma("unroll")                                                         \
  for (int im = 0; im < 4; ++im)                                            \
    acc[IN][im] = __builtin_amdgcn_mfma_f32_16x16x32_bf16(af[MS][im], bv, acc[IN][im], 0, 0, 0); \
}

#define TRMFMA(MS, O0,O1,O2,O3,O4,O5,O6,O7)                                 \
  TR8(O0,O1,O2,O3,O4,O5,O6,O7);                                             \
  LGK(6); SB0; QUAD(MS, 0, r0, r1);                                         \
  LGK(4); SB0; QUAD(MS, 1, r2, r3);                                         \
  LGK(2); SB0; QUAD(MS, 2, r4, r5);                                         \
  LGK(0); SB0; QUAD(MS, 3, r6, r7);

__device__ __forceinline__ void gemm_pipe(const unsigned short* __restrict__ X,
                                          const unsigned short* __restrict__ Wm,
                                          unsigned short* xt, unsigned xbase,
                                          int mbase, int lane, int t,
                                          float4v acc[4][4]) {
  unsigned tra = xbase + (unsigned)((((lane >> 4)) << 10) + ((lane & 15) << 3));
  const unsigned short* __restrict__ Wr = Wm + ((mbase >> 6) << 11) + lane * 8;

  short8 af[2][4];
  uint2v r0, r1, r2, r3, r4, r5, r6, r7;

  #pragma unroll
  for (int in = 0; in < 4; ++in)
    #pragma unroll
    for (int im = 0; im < 4; ++im)
      acc[in][im] = (float4v){0.f, 0.f, 0.f, 0.f};

  SB0; BARR; SB0;
  stage_tile(X,   0, t, xt + 0 * 2048);
  stage_tile(X,  32, t, xt + 1 * 2048);
  stage_tile(X,  64, t, xt + 2 * 2048);
  stage_tile(X,  96, t, xt + 3 * 2048);
  SB0;

  // ---- SS0: tiles 0,1 ----
  LOADA(0, 0); LOADA(1, 1);
  SB0;
  stage_tile(X, 128, t, xt + 4 * 2048);
  stage_tile(X, 160, t, xt + 5 * 2048);
  SB0;
  VMC(2); SB0; BARR; SB0;
  TRMFMA(0,     0,   512,   128,   640,   256,   768,   384,   896)
  TRMFMA(1,  4096,  4608,  4224,  4736,  4352,  4864,  4480,  4992)

  // ---- SS1: tiles 2,3 ----
  SB0;
  LOADA(0, 2); LOADA(1, 3);
  SB0;
  stage_tile(X, 192, t, xt + 6 * 2048);
  stage_tile(X, 224, t, xt + 7 * 2048);
  SB0;
  VMC(2); SB0; BARR; SB0;
  TRMFMA(0,  8192,  8704,  8320,  8832,  8448,  8960,  8576,  9088)
  TRMFMA(1, 12288, 12800, 12416, 12928, 12544, 13056, 12672, 13184)

  // ---- SS2: tiles 4,5 ----
  SB0;
  LOADA(0, 4); LOADA(1, 5);
  SB0;
  VMC(0); SB0; BARR; SB0;
  TRMFMA(0, 16384, 16896, 16512, 17024, 16640, 17152, 16768, 17280)
  TRMFMA(1, 20480, 20992, 20608, 21120, 20736, 21248, 20864, 21376)

  // ---- SS3: tiles 6,7 ----
  SB0;
  LOADA(0, 6); LOADA(1, 7);
  SB0;
  VMC(0); SB0; BARR; SB0;
  TRMFMA(0, 24576, 25088, 24704, 25216, 24832, 25344, 24960, 25472)
  TRMFMA(1, 28672, 29184, 28800, 29312, 28928, 29440, 29056, 29568)
}

// ---------------------------------------------------------------------------
// Kernel 2a: FF/GG gemms -> cosine similarity S + atomic batch min/max.
// ---------------------------------------------------------------------------
__global__ __launch_bounds__(256, 2) void k_gemm1(const unsigned short* __restrict__ xcm,
                                                  const unsigned short* __restrict__ wbf,
                                                  const float* __restrict__ bFF,
                                                  const float* __restrict__ bGG,
                                                  float* __restrict__ Sout,
                                                  unsigned int* __restrict__ mmu) {
  int blk  = blockIdx.x;
  int b    = blk >> 8;
  int pt   = blk & 255;
  int p0   = pt * 64;
  int t    = threadIdx.x;
  int wv   = t >> 6;
  int lane = t & 63;
  int q    = lane >> 4;
  int mbase = wv * 64;

  __shared__ __align__(16) unsigned short xt[8][2048];   // 32 KB: 8 X slots
  __shared__ float sred[3 * 64];       // dot, |F|^2, |G|^2 per pixel
  if (t < 192) sred[t] = 0.f;
  __syncthreads();
  unsigned xbase = (unsigned)(unsigned long long)&xt[0][0];

  const unsigned short* Xt = xcm + (((size_t)(b * 256 + pt)) << 14);

  float4v aF[4][4], aG[4][4];

  gemm_pipe(Xt + 0 * TSZ, wbf + 0 * 65536, &xt[0][0], xbase, mbase, lane, t, aF);
  gemm_pipe(Xt + 1 * TSZ, wbf + 1 * 65536, &xt[0][0], xbase, mbase, lane, t, aG);
  #pragma unroll
  for (int im = 0; im < 4; ++im) {
    float4v bvF = *(const float4v*)(bFF + mbase + im * 16 + q * 4);
    float4v bvG = *(const float4v*)(bGG + mbase + im * 16 + q * 4);
    #pragma unroll
    for (int in = 0; in < 4; ++in) { aF[in][im] += bvF; aG[in][im] += bvG; }
  }
  #pragma unroll
  for (int in = 0; in < 4; ++in) {
    float d = 0.f, nf = 0.f, ng = 0.f;
    #pragma unroll
    for (int im = 0; im < 4; ++im)
      #pragma unroll
      for (int r = 0; r < 4; ++r) {
        float f = aF[in][im][r], g = aG[in][im][r];
        d += f * g; nf += f * f; ng += g * g;
      }
    d  += __shfl_xor(d, 16);  d  += __shfl_xor(d, 32);
    nf += __shfl_xor(nf, 16); nf += __shfl_xor(nf, 32);
    ng += __shfl_xor(ng, 16); ng += __shfl_xor(ng, 32);
    if (lane < 16) {
      atomicAdd(&sred[0 * 64 + in * 16 + lane], d);
      atomicAdd(&sred[1 * 64 + in * 16 + lane], nf);
      atomicAdd(&sred[2 * 64 + in * 16 + lane], ng);
    }
  }
  __syncthreads();
  if (t < 64) {           // wave 0
    float d = sred[t], nf = sred[64 + t], ng = sred[128 + t];
    float sv = d / (sqrtf(nf) * sqrtf(ng));
    Sout[(size_t)b * PIX + p0 + t] = sv;
    float mn = sv, mx = sv;
    #pragma unroll
    for (int o = 32; o >= 1; o >>= 1) {
      mn = fminf(mn, __shfl_xor(mn, o));
      mx = fmaxf(mx, __shfl_xor(mx, o));
    }
    if (t == 0) {
      atomicMin(&mmu[b * 2],     fkey(mn));
      atomicMax(&mmu[b * 2 + 1], fkey(mx));
    }
  }
}

// ---------------------------------------------------------------------------
// Kernel 2b: EE/HH gemms fused with the blend: out = S_n*EE + (1-S_n)*HH.
// ---------------------------------------------------------------------------
__global__ __launch_bounds__(256, 2) void k_gemm2(const unsigned short* __restrict__ xcm,
                                                  const unsigned short* __restrict__ wbf,
                                                  const float* __restrict__ bEE,
                                                  const float* __restrict__ bHH,
                                                  const float* __restrict__ S,
                                                  const unsigned int* __restrict__ mmu,
                                                  float* __restrict__ out) {
  int blk  = blockIdx.x;
  int b    = blk >> 8;
  int pt   = blk & 255;
  int p0   = pt * 64;
  int t    = threadIdx.x;
  int wv   = t >> 6;
  int lane = t & 63;
  int col  = lane & 15;
  int q    = lane >> 4;
  int mbase = wv * 64;

  __shared__ __align__(16) unsigned short xt[8][2048];   // 32 KB: 8 X slots
  unsigned xbase = (unsigned)(unsigned long long)&xt[0][0];

  const unsigned short* Xt = xcm + (((size_t)(b * 256 + pt)) << 14);

  float4v aE[4][4], aH[4][4];

  gemm_pipe(Xt + 2 * TSZ, wbf + 2 * 65536, &xt[0][0], xbase, mbase, lane, t, aE);
  gemm_pipe(Xt + 3 * TSZ, wbf + 3 * 65536, &xt[0][0], xbase, mbase, lane, t, aH);

  float mn = funkey(mmu[b * 2]), mx = funkey(mmu[b * 2 + 1]);
  float inv = 1.f / (mx - mn);
  float sn[4];
  #pragma unroll
  for (int in = 0; in < 4; ++in)
    sn[in] = (S[(size_t)b * PIX + p0 + in * 16 + col] - mn) * inv;

  #pragma unroll
  for (int im = 0; im < 4; ++im) {
    float4v bvE = *(const float4v*)(bEE + mbase + im * 16 + q * 4);
    float4v bvH = *(const float4v*)(bHH + mbase + im * 16 + q * 4);
    #pragma unroll
    for (int in = 0; in < 4; ++in)
      #pragma unroll
      for (int r = 0; r < 4; ++r) {
        int m = mbase + im * 16 + q * 4 + r;
        float e = aE[in][im][r] + bvE[r];
        float h = aH[in][im][r] + bvH[r];
        out[((size_t)(b * 256 + m)) * PIX + p0 + in * 16 + col] = h + sn[in] * (e - h);
      }
  }
}

// ---------------------------------------------------------------------------
// Workspace layout (bytes):
//   0          : xcm   4 tensors bf16 (tiled)    = 268,435,456
//   268435456  : wbf   4x256x256 bf16 (packed)   =     524,288
//   268959744  : S     fp32 8x16384              =     524,288
//   269484032  : mmu   u32 keys 8x2              =          64
// total ~269.5 MB
// ---------------------------------------------------------------------------
extern "C" void kernel_launch(void* const* d_in, const int* in_sizes, int n_in,
                              void* d_out, int out_size, void* d_ws, size_t ws_size,
                              hipStream_t stream) {
  const float* front = (const float*)d_in[0];
  const float* back  = (const float*)d_in[1];
  // d_in[2] = mask (unused by reference)
  const float* we = (const float*)d_in[3];
  const float* be = (const float*)d_in[4];
  const float* wf = (const float*)d_in[5];
  const float* bf = (const float*)d_in[6];
  const float* wg = (const float*)d_in[7];
  const float* bg = (const float*)d_in[8];
  const float* wh = (const float*)d_in[9];
  const float* bh = (const float*)d_in[10];

  char* ws = (char*)d_ws;
  unsigned short* xcm  = (unsigned short*)(ws);
  unsigned short* wbf  = (unsigned short*)(ws + 268435456);
  float*          S    = (float*)(ws + 268959744);
  unsigned int*   mmu  = (unsigned int*)(ws + 269484032);
  float*          out  = (float*)d_out;

  k_stats <<<17408, 256, 0, stream>>>(front, back, we, wf, wg, wh, xcm, wbf, mmu);
  k_gemm1 <<<2048,  256, 0, stream>>>(xcm, wbf, bf, bg, S, mmu);
  k_gemm2 <<<2048,  256, 0, stream>>>(xcm, wbf, be, bh, S, mmu, out);
}